// Round 2
// baseline (15340.259 us; speedup 1.0000x reference)
//
#include <hip/hip_runtime.h>

#define BB 512
#define SS 256
#define HH 128
#define NC 10

// =====================================================================
// proj_k: out[m][j] = b1[j] + b2[j] + sum_d A[m][d] * W[j][d]
// A: (M=BB*SS, K) row-major. W: (HH, K) row-major. out: (M, HH).
// In-place safe (A == out): each block reads only rows [m0,m0+128) across
// all k-chunks, then writes the same rows in the epilogue.
// 256 threads, 8x8 register tile per thread (128 rows x 128 cols / block).
// =====================================================================
template<int K>
__global__ __launch_bounds__(256, 2)
void proj_k(const float* __restrict__ A, const float* __restrict__ W,
            const float* __restrict__ b1, const float* __restrict__ b2,
            float* __restrict__ out)
{
    constexpr int KC = 16;
    const int tid = threadIdx.x;
    const int tx = tid & 15, ty = tid >> 4;
    const size_t m0 = (size_t)blockIdx.x * 128;

    __shared__ float Wt[K][132];    // W transposed: Wt[k][j]
    __shared__ float Ast[KC][132];  // A chunk transposed: Ast[k][row]

    // stage W transposed (once per block; W is small and L2-hot)
    constexpr int KQ = K / 4;
    for (int idx = tid; idx < HH * KQ; idx += 256) {
        const int j = idx / KQ, kq = idx % KQ;
        const float4 w = *(const float4*)(W + (size_t)j * K + 4 * kq);
        Wt[4*kq+0][j] = w.x; Wt[4*kq+1][j] = w.y;
        Wt[4*kq+2][j] = w.z; Wt[4*kq+3][j] = w.w;
    }

    float acc[8][8];
    {
        float4 p0 = *(const float4*)(b1 + 8*tx), p1 = *(const float4*)(b1 + 8*tx + 4);
        float4 q0 = *(const float4*)(b2 + 8*tx), q1 = *(const float4*)(b2 + 8*tx + 4);
        const float bj[8] = {p0.x+q0.x, p0.y+q0.y, p0.z+q0.z, p0.w+q0.w,
                             p1.x+q1.x, p1.y+q1.y, p1.z+q1.z, p1.w+q1.w};
        #pragma unroll
        for (int i = 0; i < 8; ++i)
            #pragma unroll
            for (int c = 0; c < 8; ++c) acc[i][c] = bj[c];
    }

    #pragma unroll
    for (int kc = 0; kc < K; kc += KC) {
        const int kcur = (K - kc) < KC ? (K - kc) : KC;
        const int q = kcur / 4;
        __syncthreads();   // protect Ast from previous chunk's readers
        for (int idx = tid; idx < 128 * q; idx += 256) {
            const int row = idx / q, kq = idx % q;
            const float4 a = *(const float4*)(A + (m0 + row) * K + kc + 4 * kq);
            Ast[4*kq+0][row] = a.x; Ast[4*kq+1][row] = a.y;
            Ast[4*kq+2][row] = a.z; Ast[4*kq+3][row] = a.w;
        }
        __syncthreads();
        #pragma unroll
        for (int k = 0; k < KC; ++k) {
            if (k >= kcur) break;
            const float4 A0 = *(const float4*)(&Ast[k][8*ty]);
            const float4 A1 = *(const float4*)(&Ast[k][8*ty+4]);
            const float4 B0 = *(const float4*)(&Wt[kc+k][8*tx]);
            const float4 B1 = *(const float4*)(&Wt[kc+k][8*tx+4]);
            const float av[8] = {A0.x,A0.y,A0.z,A0.w,A1.x,A1.y,A1.z,A1.w};
            const float bv[8] = {B0.x,B0.y,B0.z,B0.w,B1.x,B1.y,B1.z,B1.w};
            #pragma unroll
            for (int i = 0; i < 8; ++i)
                #pragma unroll
                for (int c = 0; c < 8; ++c) acc[i][c] += av[i] * bv[c];
        }
    }

    #pragma unroll
    for (int i = 0; i < 8; ++i) {
        float4 r0 = {acc[i][0], acc[i][1], acc[i][2], acc[i][3]};
        float4 r1 = {acc[i][4], acc[i][5], acc[i][6], acc[i][7]};
        float* op = out + (m0 + 8*ty + i) * HH + 8*tx;
        *(float4*)op = r0; *(float4*)(op + 4) = r1;
    }
}

// =====================================================================
// scan_k: h[s] = tanh(xw[s] + h[s-1] @ W_hh^T), in-place over buf (B,S,H).
// One block per batch row. 256 threads: g = tid>>2 owns outputs {2g,2g+1},
// r = tid&3 owns k-chunk [32r,32r+32). 64 weight floats pinned in VGPRs.
// h in LDS with 36-stride swizzle (conflict-free b128 broadcast reads).
// xw staged through LDS in 8-step double-buffered chunks so the barrier
// vmcnt drain is paid once per 8 steps.
// =====================================================================
template<bool WRITE_ALL>
__global__ __launch_bounds__(256, 2)
void scan_k(float* __restrict__ buf, float* __restrict__ hfin,
            const float* __restrict__ w_hh)
{
    const int b   = blockIdx.x;
    const int tid = threadIdx.x;
    const int g = tid >> 2;         // 0..63 -> outputs 2g, 2g+1
    const int r = tid & 3;          // k-chunk [32r, 32r+32)
    const int jj = 2*g + (r & 1);   // column this lane finalizes (if r<2)

    // weights: rows 2g, 2g+1, cols [32r, 32r+32)
    float w0[32], w1[32];
    {
        const float* p0 = w_hh + (size_t)(2*g)   * HH + 32*r;
        const float* p1 = w_hh + (size_t)(2*g+1) * HH + 32*r;
        #pragma unroll
        for (int k = 0; k < 32; k += 4) {
            const float4 a = *(const float4*)(p0 + k);
            const float4 c = *(const float4*)(p1 + k);
            w0[k]=a.x; w0[k+1]=a.y; w0[k+2]=a.z; w0[k+3]=a.w;
            w1[k]=c.x; w1[k+1]=c.y; w1[k+2]=c.z; w1[k+3]=c.w;
        }
    }
    #pragma unroll
    for (int k = 0; k < 32; ++k) { asm volatile("" : "+v"(w0[k]), "+v"(w1[k])); }

    __shared__ float h_sw[144];          // h[k] at word (k&31) + 36*(k>>5)
    __shared__ float xwl[2][8][HH];      // 8-step xw double buffer

    float* const rowbase = buf + (size_t)b * SS * HH;
    const int t   = tid >> 5;            // staging: step-in-chunk
    const int pos = (tid & 31) * 4;      // staging: column (float4)

    if (tid < 144) h_sw[tid] = 0.f;
    {   // stage chunk 0 (steps 0..7)
        const float4 v = *(const float4*)(rowbase + (size_t)t * HH + pos);
        *(float4*)(&xwl[0][t][pos]) = v;
    }
    __syncthreads();

    for (int s = 0; s < SS; ++s) {
        const int ph = s & 7, cb = (s >> 3) & 1;
        const bool do_stage = (ph == 0) && (s + 8 < SS);
        float4 stg;
        if (do_stage)
            stg = *(const float4*)(rowbase + (size_t)(s + 8 + t) * HH + pos);

        // two outputs x 32-wide chunk, 4 accumulation chains
        float p00 = 0.f, p01 = 0.f, p10 = 0.f, p11 = 0.f;
        const float* hb = h_sw + 36 * r;
        #pragma unroll
        for (int i = 0; i < 8; i += 2) {
            const float4 h0 = *(const float4*)(hb + 4*i);
            const float4 h1 = *(const float4*)(hb + 4*i + 4);
            p00 += h0.x*w0[4*i]   + h0.y*w0[4*i+1] + h0.z*w0[4*i+2] + h0.w*w0[4*i+3];
            p10 += h0.x*w1[4*i]   + h0.y*w1[4*i+1] + h0.z*w1[4*i+2] + h0.w*w1[4*i+3];
            p01 += h1.x*w0[4*i+4] + h1.y*w0[4*i+5] + h1.z*w0[4*i+6] + h1.w*w0[4*i+7];
            p11 += h1.x*w1[4*i+4] + h1.y*w1[4*i+5] + h1.z*w1[4*i+6] + h1.w*w1[4*i+7];
        }
        float a0 = p00 + p01, a1 = p10 + p11;
        a0 += __shfl_xor(a0, 1); a0 += __shfl_xor(a0, 2);
        a1 += __shfl_xor(a1, 1); a1 += __shfl_xor(a1, 2);

        const float z = ((r & 1) ? a1 : a0) + xwl[cb][ph][jj];
        const float e = __expf(2.f * z);
        const float hnew = 1.f - 2.f * __builtin_amdgcn_rcpf(1.f + e);  // tanh(z)

        __syncthreads();                 // all h_sw / xwl reads done
        if (r < 2) {
            h_sw[(jj & 31) + 36 * (jj >> 5)] = hnew;
            if (WRITE_ALL) rowbase[(size_t)s * HH + jj] = hnew;
            else if (s == SS - 1) hfin[(size_t)b * HH + jj] = hnew;
        }
        if (do_stage) *(float4*)(&xwl[cb ^ 1][t][pos]) = stg;
        __syncthreads();                 // writes visible before next reads
    }
}

// =====================================================================
__global__ __launch_bounds__(128)
void fc_k(const float* __restrict__ hlast, const float* __restrict__ fc_w,
          const float* __restrict__ fc_b, float* __restrict__ out)
{
    const int b = blockIdx.x;
    const int tid = threadIdx.x;
    __shared__ __align__(16) float h[HH];
    h[tid] = hlast[(size_t)b * HH + tid];
    __syncthreads();
    if (tid < NC) {
        float a = fc_b[tid];
        const float* wr = fc_w + tid * HH;
        #pragma unroll 4
        for (int k = 0; k < HH; ++k) a += h[k] * wr[k];
        out[(size_t)b * NC + tid] = a;
    }
}

extern "C" void kernel_launch(void* const* d_in, const int* in_sizes, int n_in,
                              void* d_out, int out_size, void* d_ws, size_t ws_size,
                              hipStream_t stream) {
    const float* x     = (const float*)d_in[0];   // (512,256,28)
    const float* w_ih0 = (const float*)d_in[1];   // (128,28)
    const float* w_hh0 = (const float*)d_in[2];   // (128,128)
    const float* b_ih0 = (const float*)d_in[3];
    const float* b_hh0 = (const float*)d_in[4];
    const float* w_ih  = (const float*)d_in[5];   // (3,128,128)
    const float* w_hh  = (const float*)d_in[6];   // (3,128,128)
    const float* b_ih  = (const float*)d_in[7];   // (3,128)
    const float* b_hh  = (const float*)d_in[8];
    const float* fc_w  = (const float*)d_in[9];   // (10,128)
    const float* fc_b  = (const float*)d_in[10];
    float* out = (float*)d_out;

    float* buf  = (float*)d_ws;                   // (B,S,H) fp32 = 64 MB
    float* hfin = buf + (size_t)BB * SS * HH;     // (B,H)

    const int PGRID = (BB * SS) / 128;            // 1024

    // layer 0
    proj_k<28><<<PGRID, 256, 0, stream>>>(x, w_ih0, b_ih0, b_hh0, buf);
    scan_k<true><<<BB, 256, 0, stream>>>(buf, hfin, w_hh0);
    // layers 1..3
    for (int l = 0; l < 3; ++l) {
        proj_k<128><<<PGRID, 256, 0, stream>>>(buf, w_ih + (size_t)l * HH * HH,
                                               b_ih + (size_t)l * HH,
                                               b_hh + (size_t)l * HH, buf);
        if (l < 2) scan_k<true ><<<BB, 256, 0, stream>>>(buf, hfin, w_hh + (size_t)l * HH * HH);
        else       scan_k<false><<<BB, 256, 0, stream>>>(buf, hfin, w_hh + (size_t)l * HH * HH);
    }
    fc_k<<<BB, 128, 0, stream>>>(hfin, fc_w, fc_b, out);
}

// Round 3
// 7661.236 us; speedup vs baseline: 2.0023x; 2.0023x over previous
//
#include <hip/hip_runtime.h>

#define BB 512
#define SS 256
#define HH 128
#define NC 10

// =====================================================================
// proj_k: out[m][j] = b1[j] + b2[j] + sum_d A[m][d] * W[j][d]
// A: (M, K) row-major, W: (HH, K) row-major, out: (M, HH).
// Block tile: 64 rows x 128 cols. 256 threads, each 4 rows x 8 cols
// (rows ty+16r, cols tx+16c) -> 32 acc VGPRs, no spill.
// A staged full-K in LDS once (coalesced); W staged per 32-k chunk.
// LDS strides ≡ 4 (mod 32) words -> b128 reads 2-way/broadcast = free.
// In-place safe (A == out): all global A reads happen before any store.
// =====================================================================
template<int K>
__global__ __launch_bounds__(256, 3)
void proj_k(const float* __restrict__ A, const float* __restrict__ W,
            const float* __restrict__ b1, const float* __restrict__ b2,
            float* __restrict__ out)
{
    constexpr int AS = ((K + 31) / 32) * 32 + 4;      // A LDS stride (words)
    constexpr int KQ = K / 4;                         // float4 per A row
    constexpr int KCW = (K < 32) ? K : 32;            // W chunk size
    constexpr int WQ = KCW / 4;                       // float4 per W chunk row
    const int tid = threadIdx.x;
    const int tx = tid & 15;                          // col group: cols tx+16c
    const int ty = tid >> 4;                          // row group: rows ty+16r
    const size_t m0 = (size_t)blockIdx.x * 64;

    __shared__ float Arm[64 * AS];
    __shared__ float Wst[128 * 36];

    // stage full A tile (64 x K), coalesced (tile is contiguous in global)
    for (int idx = tid; idx < 64 * KQ; idx += 256) {
        const int row = idx / KQ, kq = idx % KQ;
        const float4 v = *(const float4*)(A + (m0 + row) * K + 4 * kq);
        *(float4*)(&Arm[row * AS + 4 * kq]) = v;
    }

    float acc[4][8];
    #pragma unroll
    for (int c = 0; c < 8; ++c) {
        const int j = tx + 16 * c;
        const float bj = b1[j] + b2[j];
        #pragma unroll
        for (int r = 0; r < 4; ++r) acc[r][c] = bj;
    }

    #pragma unroll
    for (int kc = 0; kc < K; kc += KCW) {
        __syncthreads();   // Arm staged (first iter) / Wst readers done
        for (int idx = tid; idx < 128 * WQ; idx += 256) {
            const int col = idx / WQ, q = idx % WQ;
            const float4 v = *(const float4*)(W + (size_t)col * K + kc + 4 * q);
            *(float4*)(&Wst[col * 36 + 4 * q]) = v;
        }
        __syncthreads();
        #pragma unroll
        for (int q = 0; q < WQ; ++q) {
            float4 av[4], wv[8];
            #pragma unroll
            for (int r = 0; r < 4; ++r)
                av[r] = *(const float4*)(&Arm[(ty + 16 * r) * AS + kc + 4 * q]);
            #pragma unroll
            for (int c = 0; c < 8; ++c)
                wv[c] = *(const float4*)(&Wst[(tx + 16 * c) * 36 + 4 * q]);
            #pragma unroll
            for (int r = 0; r < 4; ++r)
                #pragma unroll
                for (int c = 0; c < 8; ++c)
                    acc[r][c] += av[r].x * wv[c].x + av[r].y * wv[c].y
                               + av[r].z * wv[c].z + av[r].w * wv[c].w;
        }
    }

    #pragma unroll
    for (int r = 0; r < 4; ++r)
        #pragma unroll
        for (int c = 0; c < 8; ++c)
            out[(m0 + ty + 16 * r) * HH + tx + 16 * c] = acc[r][c];
}

// =====================================================================
// scan_k: h[s] = tanh(xw[s] + h[s-1] @ W_hh^T), over buf (B,S,H) in place.
// One block per batch row, 128 threads; thread j owns column j with the
// full W_hh row (128 floats) resident in VGPRs -> no reduction, no shfl.
// h ping-pong in LDS; all h reads are same-address broadcasts (free).
// One barrier per step. xw prefetched one step ahead (coalesced 512 B).
// =====================================================================
template<bool WRITE_ALL>
__global__ __launch_bounds__(128, 2)
void scan_k(float* __restrict__ buf, float* __restrict__ hfin,
            const float* __restrict__ w_hh)
{
    const int b = blockIdx.x;
    const int j = threadIdx.x;
    float* const row = buf + (size_t)b * SS * HH;

    float w[HH];
    {
        const float* wr = w_hh + (size_t)j * HH;
        #pragma unroll
        for (int k = 0; k < HH; k += 4) {
            const float4 v = *(const float4*)(wr + k);
            w[k] = v.x; w[k+1] = v.y; w[k+2] = v.z; w[k+3] = v.w;
        }
    }
    #pragma unroll
    for (int k = 0; k < HH; ++k) asm volatile("" : "+v"(w[k]));

    __shared__ float h[2][HH];
    h[0][j] = 0.f;
    float xw = row[j];                     // xw[s=0]
    __syncthreads();

    int cur = 0;
    for (int s = 0; s < SS; ++s) {
        float xwn = 0.f;
        if (s + 1 < SS) xwn = row[(size_t)(s + 1) * HH + j];

        float a0 = 0.f, a1 = 0.f, a2 = 0.f, a3 = 0.f;
        const float* hb = h[cur];
        #pragma unroll
        for (int k = 0; k < HH; k += 16) {
            const float4 h0 = *(const float4*)(hb + k);
            const float4 h1 = *(const float4*)(hb + k + 4);
            const float4 h2 = *(const float4*)(hb + k + 8);
            const float4 h3 = *(const float4*)(hb + k + 12);
            a0 += h0.x*w[k+0]  + h0.y*w[k+1]  + h0.z*w[k+2]  + h0.w*w[k+3];
            a1 += h1.x*w[k+4]  + h1.y*w[k+5]  + h1.z*w[k+6]  + h1.w*w[k+7];
            a2 += h2.x*w[k+8]  + h2.y*w[k+9]  + h2.z*w[k+10] + h2.w*w[k+11];
            a3 += h3.x*w[k+12] + h3.y*w[k+13] + h3.z*w[k+14] + h3.w*w[k+15];
        }
        const float z = xw + ((a0 + a1) + (a2 + a3));
        const float e = __expf(2.f * z);
        const float hnew = 1.f - 2.f * __builtin_amdgcn_rcpf(1.f + e);   // tanh(z)

        h[cur ^ 1][j] = hnew;
        if (WRITE_ALL) row[(size_t)s * HH + j] = hnew;
        else if (s == SS - 1) hfin[(size_t)b * HH + j] = hnew;
        __syncthreads();
        xw = xwn; cur ^= 1;
    }
}

// =====================================================================
__global__ __launch_bounds__(128)
void fc_k(const float* __restrict__ hlast, const float* __restrict__ fc_w,
          const float* __restrict__ fc_b, float* __restrict__ out)
{
    const int b = blockIdx.x;
    const int tid = threadIdx.x;
    __shared__ __align__(16) float h[HH];
    h[tid] = hlast[(size_t)b * HH + tid];
    __syncthreads();
    if (tid < NC) {
        float a = fc_b[tid];
        const float* wr = fc_w + tid * HH;
        #pragma unroll 4
        for (int k = 0; k < HH; ++k) a += h[k] * wr[k];
        out[(size_t)b * NC + tid] = a;
    }
}

extern "C" void kernel_launch(void* const* d_in, const int* in_sizes, int n_in,
                              void* d_out, int out_size, void* d_ws, size_t ws_size,
                              hipStream_t stream) {
    const float* x     = (const float*)d_in[0];   // (512,256,28)
    const float* w_ih0 = (const float*)d_in[1];   // (128,28)
    const float* w_hh0 = (const float*)d_in[2];   // (128,128)
    const float* b_ih0 = (const float*)d_in[3];
    const float* b_hh0 = (const float*)d_in[4];
    const float* w_ih  = (const float*)d_in[5];   // (3,128,128)
    const float* w_hh  = (const float*)d_in[6];   // (3,128,128)
    const float* b_ih  = (const float*)d_in[7];   // (3,128)
    const float* b_hh  = (const float*)d_in[8];
    const float* fc_w  = (const float*)d_in[9];   // (10,128)
    const float* fc_b  = (const float*)d_in[10];
    float* out = (float*)d_out;

    float* buf  = (float*)d_ws;                   // (B,S,H) fp32 = 64 MB
    float* hfin = buf + (size_t)BB * SS * HH;     // (B,H)

    const int PGRID = (BB * SS) / 64;             // 2048 blocks

    // layer 0
    proj_k<28><<<PGRID, 256, 0, stream>>>(x, w_ih0, b_ih0, b_hh0, buf);
    scan_k<true><<<BB, 128, 0, stream>>>(buf, hfin, w_hh0);
    // layers 1..3
    for (int l = 0; l < 3; ++l) {
        proj_k<128><<<PGRID, 256, 0, stream>>>(buf, w_ih + (size_t)l * HH * HH,
                                               b_ih + (size_t)l * HH,
                                               b_hh + (size_t)l * HH, buf);
        if (l < 2) scan_k<true ><<<BB, 128, 0, stream>>>(buf, hfin, w_hh + (size_t)l * HH * HH);
        else       scan_k<false><<<BB, 128, 0, stream>>>(buf, hfin, w_hh + (size_t)l * HH * HH);
    }
    fc_k<<<BB, 128, 0, stream>>>(hfin, fc_w, fc_b, out);
}

// Round 4
// 1117.891 us; speedup vs baseline: 13.7225x; 6.8533x over previous
//
#include <hip/hip_runtime.h>

#define BB 512
#define SS 256
#define HH 128
#define NC 10

// =====================================================================
// proj_k: out[m][j] = b1[j] + b2[j] + sum_d A[m][d] * W[j][d]
// A: (M, K) row-major, W: (HH, K) row-major, out: (M, HH).
// Block tile: 64 rows x 128 cols. 256 threads, each 4 rows x 8 cols.
// launch_bounds(256,1): empirical VGPR cap ~256 (cap=256/arg on this
// toolchain — R2/R3 showed (256,2)->128, (256,3)->84 with acc spilled
// to scratch = GBs of FETCH/WRITE). Live set kept ~60: one wv fragment
// at a time, no kc-loop unroll.
// In-place safe (A == out): block reads only its own rows, writes last.
// =====================================================================
template<int K>
__global__ __launch_bounds__(256, 1)
void proj_k(const float* __restrict__ A, const float* __restrict__ W,
            const float* __restrict__ b1, const float* __restrict__ b2,
            float* __restrict__ out)
{
    constexpr int AS = ((K + 31) / 32) * 32 + 4;      // A LDS stride (words)
    constexpr int KQ = K / 4;                         // float4 per A row
    constexpr int KCW = (K < 32) ? K : 32;            // W chunk size
    constexpr int WQ = KCW / 4;                       // float4 per W chunk row
    const int tid = threadIdx.x;
    const int tx = tid & 15;                          // cols tx+16c
    const int ty = tid >> 4;                          // rows ty+16r
    const size_t m0 = (size_t)blockIdx.x * 64;

    __shared__ float Arm[64 * AS];
    __shared__ float Wst[128 * 36];

    // stage full A tile (64 x K), coalesced
    for (int idx = tid; idx < 64 * KQ; idx += 256) {
        const int row = idx / KQ, kq = idx % KQ;
        const float4 v = *(const float4*)(A + (m0 + row) * K + 4 * kq);
        *(float4*)(&Arm[row * AS + 4 * kq]) = v;
    }

    float acc[4][8];
    #pragma unroll
    for (int c = 0; c < 8; ++c) {
        const int j = tx + 16 * c;
        const float bj = b1[j] + b2[j];
        #pragma unroll
        for (int r = 0; r < 4; ++r) acc[r][c] = bj;
    }

    #pragma unroll 1
    for (int kc = 0; kc < K; kc += KCW) {
        __syncthreads();   // Arm staged / previous Wst readers done
        for (int idx = tid; idx < 128 * WQ; idx += 256) {
            const int col = idx / WQ, q = idx % WQ;
            const float4 v = *(const float4*)(W + (size_t)col * K + kc + 4 * q);
            *(float4*)(&Wst[col * 36 + 4 * q]) = v;
        }
        __syncthreads();
        #pragma unroll 1
        for (int q = 0; q < WQ; ++q) {
            float4 av[4];
            #pragma unroll
            for (int r = 0; r < 4; ++r)
                av[r] = *(const float4*)(&Arm[(ty + 16 * r) * AS + kc + 4 * q]);
            #pragma unroll
            for (int c = 0; c < 8; ++c) {
                const float4 wv = *(const float4*)(&Wst[(tx + 16 * c) * 36 + 4 * q]);
                #pragma unroll
                for (int r = 0; r < 4; ++r)
                    acc[r][c] += av[r].x * wv.x + av[r].y * wv.y
                               + av[r].z * wv.z + av[r].w * wv.w;
            }
        }
    }

    #pragma unroll
    for (int r = 0; r < 4; ++r)
        #pragma unroll
        for (int c = 0; c < 8; ++c)
            out[(m0 + ty + 16 * r) * HH + tx + 16 * c] = acc[r][c];
}

// =====================================================================
// scan_k: h[s] = tanh(xw[s] + h[s-1] @ W_hh^T), over buf (B,S,H) in place.
// One block per batch row, 128 threads; thread j owns column j with the
// full W_hh row (128 floats) resident in VGPRs (asm-pinned).
// launch_bounds(128,1): cap 256 regs -> no spill (usage ~170).
// All h reads are wave-broadcast LDS b128 (conflict-free).
// One barrier per step; xw prefetched one step ahead (coalesced 512 B).
// =====================================================================
template<bool WRITE_ALL>
__global__ __launch_bounds__(128, 1)
void scan_k(float* __restrict__ buf, float* __restrict__ hfin,
            const float* __restrict__ w_hh)
{
    const int b = blockIdx.x;
    const int j = threadIdx.x;
    float* const row = buf + (size_t)b * SS * HH;

    float w[HH];
    {
        const float* wr = w_hh + (size_t)j * HH;
        #pragma unroll
        for (int k = 0; k < HH; k += 4) {
            const float4 v = *(const float4*)(wr + k);
            w[k] = v.x; w[k+1] = v.y; w[k+2] = v.z; w[k+3] = v.w;
        }
    }
    #pragma unroll
    for (int k = 0; k < HH; ++k) asm volatile("" : "+v"(w[k]));

    __shared__ float h[2][HH];
    h[0][j] = 0.f;
    float xw = row[j];                     // xw[s=0]
    __syncthreads();

    int cur = 0;
    for (int s = 0; s < SS; ++s) {
        float xwn = 0.f;
        if (s + 1 < SS) xwn = row[(size_t)(s + 1) * HH + j];

        float a0 = 0.f, a1 = 0.f, a2 = 0.f, a3 = 0.f;
        const float* hb = h[cur];
        #pragma unroll
        for (int k = 0; k < HH; k += 16) {
            const float4 h0 = *(const float4*)(hb + k);
            const float4 h1 = *(const float4*)(hb + k + 4);
            const float4 h2 = *(const float4*)(hb + k + 8);
            const float4 h3 = *(const float4*)(hb + k + 12);
            a0 += h0.x*w[k+0]  + h0.y*w[k+1]  + h0.z*w[k+2]  + h0.w*w[k+3];
            a1 += h1.x*w[k+4]  + h1.y*w[k+5]  + h1.z*w[k+6]  + h1.w*w[k+7];
            a2 += h2.x*w[k+8]  + h2.y*w[k+9]  + h2.z*w[k+10] + h2.w*w[k+11];
            a3 += h3.x*w[k+12] + h3.y*w[k+13] + h3.z*w[k+14] + h3.w*w[k+15];
        }
        const float z = xw + ((a0 + a1) + (a2 + a3));
        const float e = __expf(2.f * z);
        const float hnew = 1.f - 2.f * __builtin_amdgcn_rcpf(1.f + e);   // tanh(z)

        h[cur ^ 1][j] = hnew;
        if (WRITE_ALL) row[(size_t)s * HH + j] = hnew;
        else if (s == SS - 1) hfin[(size_t)b * HH + j] = hnew;
        __syncthreads();
        xw = xwn; cur ^= 1;
    }
}

// =====================================================================
__global__ __launch_bounds__(128)
void fc_k(const float* __restrict__ hlast, const float* __restrict__ fc_w,
          const float* __restrict__ fc_b, float* __restrict__ out)
{
    const int b = blockIdx.x;
    const int tid = threadIdx.x;
    __shared__ __align__(16) float h[HH];
    h[tid] = hlast[(size_t)b * HH + tid];
    __syncthreads();
    if (tid < NC) {
        float a = fc_b[tid];
        const float* wr = fc_w + tid * HH;
        #pragma unroll 4
        for (int k = 0; k < HH; ++k) a += h[k] * wr[k];
        out[(size_t)b * NC + tid] = a;
    }
}

extern "C" void kernel_launch(void* const* d_in, const int* in_sizes, int n_in,
                              void* d_out, int out_size, void* d_ws, size_t ws_size,
                              hipStream_t stream) {
    const float* x     = (const float*)d_in[0];   // (512,256,28)
    const float* w_ih0 = (const float*)d_in[1];   // (128,28)
    const float* w_hh0 = (const float*)d_in[2];   // (128,128)
    const float* b_ih0 = (const float*)d_in[3];
    const float* b_hh0 = (const float*)d_in[4];
    const float* w_ih  = (const float*)d_in[5];   // (3,128,128)
    const float* w_hh  = (const float*)d_in[6];   // (3,128,128)
    const float* b_ih  = (const float*)d_in[7];   // (3,128)
    const float* b_hh  = (const float*)d_in[8];
    const float* fc_w  = (const float*)d_in[9];   // (10,128)
    const float* fc_b  = (const float*)d_in[10];
    float* out = (float*)d_out;

    float* buf  = (float*)d_ws;                   // (B,S,H) fp32 = 64 MB
    float* hfin = buf + (size_t)BB * SS * HH;     // (B,H)

    const int PGRID = (BB * SS) / 64;             // 2048 blocks

    // layer 0
    proj_k<28><<<PGRID, 256, 0, stream>>>(x, w_ih0, b_ih0, b_hh0, buf);
    scan_k<true><<<BB, 128, 0, stream>>>(buf, hfin, w_hh0);
    // layers 1..3
    for (int l = 0; l < 3; ++l) {
        proj_k<128><<<PGRID, 256, 0, stream>>>(buf, w_ih + (size_t)l * HH * HH,
                                               b_ih + (size_t)l * HH,
                                               b_hh + (size_t)l * HH, buf);
        if (l < 2) scan_k<true ><<<BB, 128, 0, stream>>>(buf, hfin, w_hh + (size_t)l * HH * HH);
        else       scan_k<false><<<BB, 128, 0, stream>>>(buf, hfin, w_hh + (size_t)l * HH * HH);
    }
    fc_k<<<BB, 128, 0, stream>>>(hfin, fc_w, fc_b, out);
}

// Round 5
// 844.547 us; speedup vs baseline: 18.1639x; 1.3237x over previous
//
#include <hip/hip_runtime.h>

#define BB 512
#define SS 256
#define HH 128
#define NC 10

// =====================================================================
// proj_k: out[m][j] = b1[j] + b2[j] + sum_d A[m][d] * W[j][d]
// (unchanged from R4 — worked, no spill at launch_bounds(256,1))
// =====================================================================
template<int K>
__global__ __launch_bounds__(256, 1)
void proj_k(const float* __restrict__ A, const float* __restrict__ W,
            const float* __restrict__ b1, const float* __restrict__ b2,
            float* __restrict__ out)
{
    constexpr int AS = ((K + 31) / 32) * 32 + 4;
    constexpr int KQ = K / 4;
    constexpr int KCW = (K < 32) ? K : 32;
    constexpr int WQ = KCW / 4;
    const int tid = threadIdx.x;
    const int tx = tid & 15;
    const int ty = tid >> 4;
    const size_t m0 = (size_t)blockIdx.x * 64;

    __shared__ float Arm[64 * AS];
    __shared__ float Wst[128 * 36];

    for (int idx = tid; idx < 64 * KQ; idx += 256) {
        const int row = idx / KQ, kq = idx % KQ;
        const float4 v = *(const float4*)(A + (m0 + row) * K + 4 * kq);
        *(float4*)(&Arm[row * AS + 4 * kq]) = v;
    }

    float acc[4][8];
    #pragma unroll
    for (int c = 0; c < 8; ++c) {
        const int j = tx + 16 * c;
        const float bj = b1[j] + b2[j];
        #pragma unroll
        for (int r = 0; r < 4; ++r) acc[r][c] = bj;
    }

    #pragma unroll 1
    for (int kc = 0; kc < K; kc += KCW) {
        __syncthreads();
        for (int idx = tid; idx < 128 * WQ; idx += 256) {
            const int col = idx / WQ, q = idx % WQ;
            const float4 v = *(const float4*)(W + (size_t)col * K + kc + 4 * q);
            *(float4*)(&Wst[col * 36 + 4 * q]) = v;
        }
        __syncthreads();
        #pragma unroll 1
        for (int q = 0; q < WQ; ++q) {
            float4 av[4];
            #pragma unroll
            for (int r = 0; r < 4; ++r)
                av[r] = *(const float4*)(&Arm[(ty + 16 * r) * AS + kc + 4 * q]);
            #pragma unroll
            for (int c = 0; c < 8; ++c) {
                const float4 wv = *(const float4*)(&Wst[(tx + 16 * c) * 36 + 4 * q]);
                #pragma unroll
                for (int r = 0; r < 4; ++r)
                    acc[r][c] += av[r].x * wv.x + av[r].y * wv.y
                               + av[r].z * wv.z + av[r].w * wv.w;
            }
        }
    }

    #pragma unroll
    for (int r = 0; r < 4; ++r)
        #pragma unroll
        for (int c = 0; c < 8; ++c)
            out[(m0 + ty + 16 * r) * HH + tx + 16 * c] = acc[r][c];
}

// =====================================================================
// scan_k (rebuilt): h[s] = tanh(xw[s] + h[s-1] @ W_hh^T) per batch row.
// 512 threads: thread (j = tid>>2, r = tid&3) owns column j, k-chunk
// [32r,32r+32). Only 32 weight VGPRs/thread -> total live ~65 regs,
// safely under the allocator's ~84 heuristic (R4 lesson: >84 gets
// demoted). Quad reduction via 2x shfl_xor. 16 waves/CU (4/SIMD) for
// real latency hiding. h ping-pong in LDS with 36-word chunk swizzle:
// chunk r at word 36r -> the 4 r-chunks hit disjoint banks, all reads
// are 16-way broadcast b128 = conflict-free. xw staged 16 steps at a
// time (512 thr x 1 float4, coalesced, double-buffered). h written to
// global by one coop 32-lane b128 store per step. One barrier/step.
// In-place safe: xw reads are steps >= s+16, h writes are step s-1.
// =====================================================================
template<bool WRITE_ALL>
__global__ __launch_bounds__(512, 2)
void scan_k(float* __restrict__ buf, float* __restrict__ hfin,
            const float* __restrict__ w_hh)
{
    const int b   = blockIdx.x;
    const int tid = threadIdx.x;
    const int j   = tid >> 2;        // column 0..127
    const int r   = tid & 3;         // k-chunk

    float* const row = buf + (size_t)b * SS * HH;

    float w[32];
    {
        const float* wr = w_hh + (size_t)j * HH + 32 * r;
        #pragma unroll
        for (int k = 0; k < 32; k += 4) {
            const float4 v = *(const float4*)(wr + k);
            w[k] = v.x; w[k+1] = v.y; w[k+2] = v.z; w[k+3] = v.w;
        }
    }
    #pragma unroll
    for (int k = 0; k < 32; ++k) asm volatile("" : "+v"(w[k]));

    __shared__ float hsw[2][144];        // h[k] at word 36*(k>>5) + (k&31)
    __shared__ float xwl[2][16][HH];     // 16-step xw double buffer

    for (int i = tid; i < 288; i += 512) ((float*)hsw)[i] = 0.f;
    {   // stage xw for steps 0..15 (2048 floats = 512 x float4)
        const float4 v = *(const float4*)(row + tid * 4);
        *(float4*)((float*)xwl + tid * 4) = v;
    }
    __syncthreads();

    const int jw = 36 * (j >> 5) + (j & 31);   // swizzled word for column j
    const int sc = tid >> 3, sq = tid & 7;     // coop-store coords (tid<32)

    int cur = 0;
    for (int s = 0; s < SS; ++s) {
        const int ph = s & 15, cb = (s >> 4) & 1;

        if (ph == 0 && s + 16 < SS) {          // stage steps s+16 .. s+31
            const float4 v = *(const float4*)(row + (size_t)(s + 16) * HH + tid * 4);
            *(float4*)((float*)xwl[cb ^ 1] + tid * 4) = v;
        }
        if (WRITE_ALL && s > 0 && tid < 32) {  // store h_{s-1} (stable in hsw[cur])
            const float4 hv = *(const float4*)(&hsw[cur][36 * sc + 4 * sq]);
            *(float4*)(row + (size_t)(s - 1) * HH + 32 * sc + 4 * sq) = hv;
        }

        float a0 = 0.f, a1 = 0.f;
        const float* hb = &hsw[cur][36 * r];
        #pragma unroll
        for (int i = 0; i < 8; i += 2) {
            const float4 h0 = *(const float4*)(hb + 4 * i);
            const float4 h1 = *(const float4*)(hb + 4 * i + 4);
            a0 += h0.x*w[4*i]   + h0.y*w[4*i+1] + h0.z*w[4*i+2] + h0.w*w[4*i+3];
            a1 += h1.x*w[4*i+4] + h1.y*w[4*i+5] + h1.z*w[4*i+6] + h1.w*w[4*i+7];
        }
        float a = a0 + a1;
        a += __shfl_xor(a, 1);
        a += __shfl_xor(a, 2);
        const float z = a + xwl[cb][ph][j];
        const float e = __expf(2.f * z);
        const float hnew = 1.f - 2.f * __builtin_amdgcn_rcpf(1.f + e);  // tanh(z)

        if (r == 0) hsw[cur ^ 1][jw] = hnew;
        __syncthreads();
        cur ^= 1;
    }

    if (tid < 32) {                            // final h (step SS-1) from hsw[cur]
        const float4 hv = *(const float4*)(&hsw[cur][36 * sc + 4 * sq]);
        if (WRITE_ALL) *(float4*)(row + (size_t)(SS - 1) * HH + 32 * sc + 4 * sq) = hv;
        else           *(float4*)(hfin + (size_t)b * HH + 32 * sc + 4 * sq) = hv;
    }
}

// =====================================================================
__global__ __launch_bounds__(128)
void fc_k(const float* __restrict__ hlast, const float* __restrict__ fc_w,
          const float* __restrict__ fc_b, float* __restrict__ out)
{
    const int b = blockIdx.x;
    const int tid = threadIdx.x;
    __shared__ __align__(16) float h[HH];
    h[tid] = hlast[(size_t)b * HH + tid];
    __syncthreads();
    if (tid < NC) {
        float a = fc_b[tid];
        const float* wr = fc_w + tid * HH;
        #pragma unroll 4
        for (int k = 0; k < HH; ++k) a += h[k] * wr[k];
        out[(size_t)b * NC + tid] = a;
    }
}

extern "C" void kernel_launch(void* const* d_in, const int* in_sizes, int n_in,
                              void* d_out, int out_size, void* d_ws, size_t ws_size,
                              hipStream_t stream) {
    const float* x     = (const float*)d_in[0];   // (512,256,28)
    const float* w_ih0 = (const float*)d_in[1];   // (128,28)
    const float* w_hh0 = (const float*)d_in[2];   // (128,128)
    const float* b_ih0 = (const float*)d_in[3];
    const float* b_hh0 = (const float*)d_in[4];
    const float* w_ih  = (const float*)d_in[5];   // (3,128,128)
    const float* w_hh  = (const float*)d_in[6];   // (3,128,128)
    const float* b_ih  = (const float*)d_in[7];   // (3,128)
    const float* b_hh  = (const float*)d_in[8];
    const float* fc_w  = (const float*)d_in[9];   // (10,128)
    const float* fc_b  = (const float*)d_in[10];
    float* out = (float*)d_out;

    float* buf  = (float*)d_ws;                   // (B,S,H) fp32 = 64 MB
    float* hfin = buf + (size_t)BB * SS * HH;     // (B,H)

    const int PGRID = (BB * SS) / 64;             // 2048 blocks

    proj_k<28><<<PGRID, 256, 0, stream>>>(x, w_ih0, b_ih0, b_hh0, buf);
    scan_k<true><<<BB, 512, 0, stream>>>(buf, hfin, w_hh0);
    for (int l = 0; l < 3; ++l) {
        proj_k<128><<<PGRID, 256, 0, stream>>>(buf, w_ih + (size_t)l * HH * HH,
                                               b_ih + (size_t)l * HH,
                                               b_hh + (size_t)l * HH, buf);
        if (l < 2) scan_k<true ><<<BB, 512, 0, stream>>>(buf, hfin, w_hh + (size_t)l * HH * HH);
        else       scan_k<false><<<BB, 512, 0, stream>>>(buf, hfin, w_hh + (size_t)l * HH * HH);
    }
    fc_k<<<BB, 128, 0, stream>>>(hfin, fc_w, fc_b, out);
}

// Round 6
// 824.870 us; speedup vs baseline: 18.5972x; 1.0239x over previous
//
#include <hip/hip_runtime.h>

#define BB 512
#define SS 256
#define HH 128
#define NC 10

typedef float v2f __attribute__((ext_vector_type(2)));

// DPP-based fold: x += x[lane ^ m] for m in {1,2,7,15} (all within 16-lane row)
template<int CTRL>
__device__ __forceinline__ float dpp_fold(float x) {
    int t = __builtin_amdgcn_update_dpp(0, __float_as_int(x), CTRL, 0xF, 0xF, true);
    return x + __int_as_float(t);
}
__device__ __forceinline__ float red16(float x) {
    x = dpp_fold<0xB1>(x);    // xor 1 (quad_perm 1,0,3,2)
    x = dpp_fold<0x4E>(x);    // xor 2 (quad_perm 2,3,0,1)
    x = dpp_fold<0x141>(x);   // xor 7 (row_half_mirror)
    x = dpp_fold<0x140>(x);   // xor 15 (row_mirror)  -> sum over 16-lane group
    return x;
}

// =====================================================================
// proj_k: unchanged from R5 (known good: 84 VGPR, no spill, ~50 us)
// =====================================================================
template<int K>
__global__ __launch_bounds__(256, 1)
void proj_k(const float* __restrict__ A, const float* __restrict__ W,
            const float* __restrict__ b1, const float* __restrict__ b2,
            float* __restrict__ out)
{
    constexpr int AS = ((K + 31) / 32) * 32 + 4;
    constexpr int KQ = K / 4;
    constexpr int KCW = (K < 32) ? K : 32;
    constexpr int WQ = KCW / 4;
    const int tid = threadIdx.x;
    const int tx = tid & 15;
    const int ty = tid >> 4;
    const size_t m0 = (size_t)blockIdx.x * 64;

    __shared__ float Arm[64 * AS];
    __shared__ float Wst[128 * 36];

    for (int idx = tid; idx < 64 * KQ; idx += 256) {
        const int row = idx / KQ, kq = idx % KQ;
        const float4 v = *(const float4*)(A + (m0 + row) * K + 4 * kq);
        *(float4*)(&Arm[row * AS + 4 * kq]) = v;
    }

    float acc[4][8];
    #pragma unroll
    for (int c = 0; c < 8; ++c) {
        const int j = tx + 16 * c;
        const float bj = b1[j] + b2[j];
        #pragma unroll
        for (int r = 0; r < 4; ++r) acc[r][c] = bj;
    }

    #pragma unroll 1
    for (int kc = 0; kc < K; kc += KCW) {
        __syncthreads();
        for (int idx = tid; idx < 128 * WQ; idx += 256) {
            const int col = idx / WQ, q = idx % WQ;
            const float4 v = *(const float4*)(W + (size_t)col * K + kc + 4 * q);
            *(float4*)(&Wst[col * 36 + 4 * q]) = v;
        }
        __syncthreads();
        #pragma unroll 1
        for (int q = 0; q < WQ; ++q) {
            float4 av[4];
            #pragma unroll
            for (int r = 0; r < 4; ++r)
                av[r] = *(const float4*)(&Arm[(ty + 16 * r) * AS + kc + 4 * q]);
            #pragma unroll
            for (int c = 0; c < 8; ++c) {
                const float4 wv = *(const float4*)(&Wst[(tx + 16 * c) * 36 + 4 * q]);
                #pragma unroll
                for (int r = 0; r < 4; ++r)
                    acc[r][c] += av[r].x * wv.x + av[r].y * wv.y
                               + av[r].z * wv.z + av[r].w * wv.w;
            }
        }
    }

    #pragma unroll
    for (int r = 0; r < 4; ++r)
        #pragma unroll
        for (int c = 0; c < 8; ++c)
            out[(m0 + ty + 16 * r) * HH + tx + 16 * c] = acc[r][c];
}

// =====================================================================
// scan_k (R6): C=8 cols x K_chunk=8 per thread. 256 thr: j=tid>>4 (16
// col-groups of 8), r=tid&15 (k-chunk [8r,8r+8)). 64 weight floats +
// ~45 temps ~= 110 VGPR, protected by amdgpu_waves_per_eu(2,2)
// (budget 256; R5 lesson: default allocator demotes arrays to AGPRs).
// h-broadcast LDS traffic: 8 KB/block/step (8x less than R5).
// Reduction across 16 r-lanes: DPP-only butterfly (masks 1,2,7,15) —
// zero LDS-pipe cost. MACs in ext-vector float2 (v_pk_fma_f32).
// h stored at word 12*(k>>3)+(k&7): b128 reads 16B-aligned, <=2-way banks.
// One barrier per step. xw staged 8 steps at a time, double-buffered.
// =====================================================================
template<bool WRITE_ALL>
__global__ __attribute__((amdgpu_flat_work_group_size(256, 256),
                          amdgpu_waves_per_eu(2, 2)))
void scan_k(float* __restrict__ buf, float* __restrict__ hfin,
            const float* __restrict__ w_hh)
{
    const int b   = blockIdx.x;
    const int tid = threadIdx.x;
    const int j   = tid >> 4;        // col group: cols 8j..8j+7
    const int r   = tid & 15;        // k-chunk [8r, 8r+8)

    float* const row = buf + (size_t)b * SS * HH;

    // weights: w2[c][p] = {W[8j+c][8r+2p], W[8j+c][8r+2p+1]}
    v2f w2[8][4];
    #pragma unroll
    for (int c = 0; c < 8; ++c) {
        const float* wr = w_hh + (size_t)(8 * j + c) * HH + 8 * r;
        const float4 a = *(const float4*)(wr);
        const float4 d = *(const float4*)(wr + 4);
        w2[c][0] = v2f{a.x, a.y}; w2[c][1] = v2f{a.z, a.w};
        w2[c][2] = v2f{d.x, d.y}; w2[c][3] = v2f{d.z, d.w};
    }

    __shared__ float hsw[2][192];        // h[k] at word 12*(k>>3)+(k&7)
    __shared__ float xwl[2][8][HH];      // 8-step xw double buffer

    if (tid < 192) hsw[0][tid] = 0.f;
    const int t   = tid >> 5;            // staging: step-in-chunk
    const int pos = (tid & 31) * 4;      // staging: column (float4)
    {   // stage xw for steps 0..7
        const float4 v = *(const float4*)(row + (size_t)t * HH + pos);
        *(float4*)(&xwl[0][t][pos]) = v;
    }
    __syncthreads();

    const int cc = 8 * j + (r & 7);      // column this lane finalizes
    const int wsw = 12 * j + (r & 7);    // its swizzled LDS word

    int cur = 0;
    for (int s = 0; s < SS; ++s) {
        const int ph = s & 7, cb = (s >> 3) & 1;
        const bool do_stage = (ph == 0) && (s + 8 < SS);
        float4 stg;
        if (do_stage)
            stg = *(const float4*)(row + (size_t)(s + 8 + t) * HH + pos);
        if (WRITE_ALL && s > 0 && tid < 32) {   // store h_{s-1}
            const float4 hv = *(const float4*)(&hsw[cur][12 * (tid >> 1) + 4 * (tid & 1)]);
            *(float4*)(row + (size_t)(s - 1) * HH + 4 * tid) = hv;
        }

        // MAC: 8 cols x 8 k (4 packed pairs)
        const float* hb = &hsw[cur][12 * r];
        const float4 h0 = *(const float4*)(hb);
        const float4 h1 = *(const float4*)(hb + 4);
        const v2f hp[4] = {v2f{h0.x, h0.y}, v2f{h0.z, h0.w},
                           v2f{h1.x, h1.y}, v2f{h1.z, h1.w}};
        float sum[8];
        #pragma unroll
        for (int c = 0; c < 8; ++c) {
            v2f a = hp[0] * w2[c][0];
            a += hp[1] * w2[c][1];
            a += hp[2] * w2[c][2];
            a += hp[3] * w2[c][3];
            sum[c] = a.x + a.y;
        }
        // butterfly across the 16 r-lanes (DPP only)
        #pragma unroll
        for (int c = 0; c < 8; ++c) sum[c] = red16(sum[c]);

        // select this lane's column (r&7) via cndmask tree
        const int rl = r & 7;
        float a0 = (rl & 1) ? sum[1] : sum[0];
        float a1 = (rl & 1) ? sum[3] : sum[2];
        float a2 = (rl & 1) ? sum[5] : sum[4];
        float a3 = (rl & 1) ? sum[7] : sum[6];
        float b0 = (rl & 2) ? a1 : a0;
        float b1 = (rl & 2) ? a3 : a2;
        float mysum = (rl & 4) ? b1 : b0;

        const float z = mysum + xwl[cb][ph][cc];
        const float e = __expf(2.f * z);
        const float hnew = 1.f - 2.f * __builtin_amdgcn_rcpf(1.f + e);  // tanh(z)

        if (r < 8) hsw[cur ^ 1][wsw] = hnew;
        if (do_stage) *(float4*)(&xwl[cb ^ 1][t][pos]) = stg;
        __syncthreads();
        cur ^= 1;
    }

    if (tid < 32) {   // final h (step SS-1) lives in hsw[cur]
        const float4 hv = *(const float4*)(&hsw[cur][12 * (tid >> 1) + 4 * (tid & 1)]);
        if (WRITE_ALL) *(float4*)(row + (size_t)(SS - 1) * HH + 4 * tid) = hv;
        else           *(float4*)(hfin + (size_t)b * HH + 4 * tid) = hv;
    }
}

// =====================================================================
__global__ __launch_bounds__(128)
void fc_k(const float* __restrict__ hlast, const float* __restrict__ fc_w,
          const float* __restrict__ fc_b, float* __restrict__ out)
{
    const int b = blockIdx.x;
    const int tid = threadIdx.x;
    __shared__ __align__(16) float h[HH];
    h[tid] = hlast[(size_t)b * HH + tid];
    __syncthreads();
    if (tid < NC) {
        float a = fc_b[tid];
        const float* wr = fc_w + tid * HH;
        #pragma unroll 4
        for (int k = 0; k < HH; ++k) a += h[k] * wr[k];
        out[(size_t)b * NC + tid] = a;
    }
}

extern "C" void kernel_launch(void* const* d_in, const int* in_sizes, int n_in,
                              void* d_out, int out_size, void* d_ws, size_t ws_size,
                              hipStream_t stream) {
    const float* x     = (const float*)d_in[0];   // (512,256,28)
    const float* w_ih0 = (const float*)d_in[1];   // (128,28)
    const float* w_hh0 = (const float*)d_in[2];   // (128,128)
    const float* b_ih0 = (const float*)d_in[3];
    const float* b_hh0 = (const float*)d_in[4];
    const float* w_ih  = (const float*)d_in[5];   // (3,128,128)
    const float* w_hh  = (const float*)d_in[6];   // (3,128,128)
    const float* b_ih  = (const float*)d_in[7];   // (3,128)
    const float* b_hh  = (const float*)d_in[8];
    const float* fc_w  = (const float*)d_in[9];   // (10,128)
    const float* fc_b  = (const float*)d_in[10];
    float* out = (float*)d_out;

    float* buf  = (float*)d_ws;                   // (B,S,H) fp32 = 64 MB
    float* hfin = buf + (size_t)BB * SS * HH;     // (B,H)

    const int PGRID = (BB * SS) / 64;             // 2048 blocks

    proj_k<28><<<PGRID, 256, 0, stream>>>(x, w_ih0, b_ih0, b_hh0, buf);
    scan_k<true><<<BB, 256, 0, stream>>>(buf, hfin, w_hh0);
    for (int l = 0; l < 3; ++l) {
        proj_k<128><<<PGRID, 256, 0, stream>>>(buf, w_ih + (size_t)l * HH * HH,
                                               b_ih + (size_t)l * HH,
                                               b_hh + (size_t)l * HH, buf);
        if (l < 2) scan_k<true ><<<BB, 256, 0, stream>>>(buf, hfin, w_hh + (size_t)l * HH * HH);
        else       scan_k<false><<<BB, 256, 0, stream>>>(buf, hfin, w_hh + (size_t)l * HH * HH);
    }
    fc_k<<<BB, 128, 0, stream>>>(hfin, fc_w, fc_b, out);
}

// Round 7
// 772.534 us; speedup vs baseline: 19.8571x; 1.0677x over previous
//
#include <hip/hip_runtime.h>

#define BB 512
#define SS 256
#define HH 128
#define NC 10

typedef float v2f __attribute__((ext_vector_type(2)));

// keep + dpp_ctrl(give): new = keep + give[partner]   (fused v_add_f32_dpp)
template<int CTRL>
__device__ __forceinline__ float xadd(float keep, float give) {
    int t = __builtin_amdgcn_update_dpp(0, __float_as_int(give), CTRL, 0xF, 0xF, true);
    return keep + __int_as_float(t);
}

// =====================================================================
// proj_k: unchanged (known good: 84 VGPR, no spill, ~50 us/layer)
// =====================================================================
template<int K>
__global__ __launch_bounds__(256, 1)
void proj_k(const float* __restrict__ A, const float* __restrict__ W,
            const float* __restrict__ b1, const float* __restrict__ b2,
            float* __restrict__ out)
{
    constexpr int AS = ((K + 31) / 32) * 32 + 4;
    constexpr int KQ = K / 4;
    constexpr int KCW = (K < 32) ? K : 32;
    constexpr int WQ = KCW / 4;
    const int tid = threadIdx.x;
    const int tx = tid & 15;
    const int ty = tid >> 4;
    const size_t m0 = (size_t)blockIdx.x * 64;

    __shared__ float Arm[64 * AS];
    __shared__ float Wst[128 * 36];

    for (int idx = tid; idx < 64 * KQ; idx += 256) {
        const int row = idx / KQ, kq = idx % KQ;
        const float4 v = *(const float4*)(A + (m0 + row) * K + 4 * kq);
        *(float4*)(&Arm[row * AS + 4 * kq]) = v;
    }

    float acc[4][8];
    #pragma unroll
    for (int c = 0; c < 8; ++c) {
        const int j = tx + 16 * c;
        const float bj = b1[j] + b2[j];
        #pragma unroll
        for (int r = 0; r < 4; ++r) acc[r][c] = bj;
    }

    #pragma unroll 1
    for (int kc = 0; kc < K; kc += KCW) {
        __syncthreads();
        for (int idx = tid; idx < 128 * WQ; idx += 256) {
            const int col = idx / WQ, q = idx % WQ;
            const float4 v = *(const float4*)(W + (size_t)col * K + kc + 4 * q);
            *(float4*)(&Wst[col * 36 + 4 * q]) = v;
        }
        __syncthreads();
        #pragma unroll 1
        for (int q = 0; q < WQ; ++q) {
            float4 av[4];
            #pragma unroll
            for (int r = 0; r < 4; ++r)
                av[r] = *(const float4*)(&Arm[(ty + 16 * r) * AS + kc + 4 * q]);
            #pragma unroll
            for (int c = 0; c < 8; ++c) {
                const float4 wv = *(const float4*)(&Wst[(tx + 16 * c) * 36 + 4 * q]);
                #pragma unroll
                for (int r = 0; r < 4; ++r)
                    acc[r][c] += av[r].x * wv.x + av[r].y * wv.y
                               + av[r].z * wv.z + av[r].w * wv.w;
            }
        }
    }

    #pragma unroll
    for (int r = 0; r < 4; ++r)
        #pragma unroll
        for (int c = 0; c < 8; ++c)
            out[(m0 + ty + 16 * r) * HH + tx + 16 * c] = acc[r][c];
}

// =====================================================================
// scan_k (R7): R6 shape (256 thr; j=tid>>4: 8 cols; r=tid&15: 8-wide k)
// but the 16-lane reduction is a reduce-scatter tree:
//   step1 xor1 (DPP quad_perm 0xB1): 8 vals -> 4
//   step2 xor2 (DPP quad_perm 0x4E): 4 -> 2
//   step3 xor8 (DPP row_ror:8 0x128): 2 -> 1
//   step4 xor4 (ds_swizzle 0x101F — DPP can't do xor4): final sum
// Lane r holds column d = (r&3)|((r&8)>>1); copies at r and r^4;
// lanes with (r&4)==0 write h. No select tree (~23 vs ~71 insts).
// =====================================================================
template<bool WRITE_ALL>
__global__ __attribute__((amdgpu_flat_work_group_size(256, 256),
                          amdgpu_waves_per_eu(2, 2)))
void scan_k(float* __restrict__ buf, float* __restrict__ hfin,
            const float* __restrict__ w_hh)
{
    const int b   = blockIdx.x;
    const int tid = threadIdx.x;
    const int j   = tid >> 4;        // col group: cols 8j..8j+7
    const int r   = tid & 15;        // k-chunk [8r, 8r+8)

    float* const row = buf + (size_t)b * SS * HH;

    // weights: w2[c][p] = {W[8j+c][8r+2p], W[8j+c][8r+2p+1]}
    v2f w2[8][4];
    #pragma unroll
    for (int c = 0; c < 8; ++c) {
        const float* wr = w_hh + (size_t)(8 * j + c) * HH + 8 * r;
        const float4 a = *(const float4*)(wr);
        const float4 d = *(const float4*)(wr + 4);
        w2[c][0] = v2f{a.x, a.y}; w2[c][1] = v2f{a.z, a.w};
        w2[c][2] = v2f{d.x, d.y}; w2[c][3] = v2f{d.z, d.w};
    }

    __shared__ float hsw[2][192];        // h[k] at word 12*(k>>3)+(k&7)
    __shared__ float xwl[2][8][HH];      // 8-step xw double buffer

    if (tid < 192) hsw[0][tid] = 0.f;
    const int t   = tid >> 5;            // staging: step-in-chunk
    const int pos = (tid & 31) * 4;      // staging: column (float4)
    {   // stage xw for steps 0..7
        const float4 v = *(const float4*)(row + (size_t)t * HH + pos);
        *(float4*)(&xwl[0][t][pos]) = v;
    }
    __syncthreads();

    const bool bit0 = (r & 1) != 0;
    const bool bit1 = (r & 2) != 0;
    const int  d    = (r & 3) | ((r & 8) >> 1);   // my column within group
    const int  cc   = 8 * j + d;                  // global column
    const int  wsw  = 12 * j + d;                 // its swizzled LDS word
    const bool writer = (r & 4) == 0;

    int cur = 0;
    for (int s = 0; s < SS; ++s) {
        const int ph = s & 7, cb = (s >> 3) & 1;
        const bool do_stage = (ph == 0) && (s + 8 < SS);
        float4 stg;
        if (do_stage)
            stg = *(const float4*)(row + (size_t)(s + 8 + t) * HH + pos);
        if (WRITE_ALL && s > 0 && tid < 32) {   // store h_{s-1}
            const float4 hv = *(const float4*)(&hsw[cur][12 * (tid >> 1) + 4 * (tid & 1)]);
            *(float4*)(row + (size_t)(s - 1) * HH + 4 * tid) = hv;
        }
        const float myxw = xwl[cb][ph][cc];     // independent: issue early

        // MAC: 8 cols x 8 k (4 packed pairs each)
        const float* hb = &hsw[cur][12 * r];
        const float4 h0 = *(const float4*)(hb);
        const float4 h1 = *(const float4*)(hb + 4);
        const v2f hp[4] = {v2f{h0.x, h0.y}, v2f{h0.z, h0.w},
                           v2f{h1.x, h1.y}, v2f{h1.z, h1.w}};
        float v[8];
        #pragma unroll
        for (int c = 0; c < 8; ++c) {
            v2f a = hp[0] * w2[c][0];
            a += hp[1] * w2[c][1];
            a += hp[2] * w2[c][2];
            a += hp[3] * w2[c][3];
            v[c] = a.x + a.y;
        }

        // reduce-scatter across the 16 r-lanes
        // step1: xor1 — keep col-bit0 == r&1
        float u0 = xadd<0xB1>(bit0 ? v[1] : v[0], bit0 ? v[0] : v[1]);
        float u1 = xadd<0xB1>(bit0 ? v[3] : v[2], bit0 ? v[2] : v[3]);
        float u2 = xadd<0xB1>(bit0 ? v[5] : v[4], bit0 ? v[4] : v[5]);
        float u3 = xadd<0xB1>(bit0 ? v[7] : v[6], bit0 ? v[6] : v[7]);
        // step2: xor2 — keep col-bit1 == r&2
        float t0 = xadd<0x4E>(bit1 ? u1 : u0, bit1 ? u0 : u1);
        float t1 = xadd<0x4E>(bit1 ? u3 : u2, bit1 ? u2 : u3);
        // step3: xor8 (row_ror:8) — keep col-bit2 == r&8
        const bool bit3 = (r & 8) != 0;
        float q = xadd<0x128>(bit3 ? t1 : t0, bit3 ? t0 : t1);
        // step4: xor4 via ds_swizzle (both copies end complete)
        {
            int tq = __builtin_amdgcn_ds_swizzle(__float_as_int(q), 0x101F);
            q += __int_as_float(tq);
        }

        const float z = q + myxw;
        const float e = __expf(2.f * z);
        const float hnew = 1.f - 2.f * __builtin_amdgcn_rcpf(1.f + e);  // tanh(z)

        if (writer) hsw[cur ^ 1][wsw] = hnew;
        if (do_stage) *(float4*)(&xwl[cb ^ 1][t][pos]) = stg;
        __syncthreads();
        cur ^= 1;
    }

    if (tid < 32) {   // final h (step SS-1) lives in hsw[cur]
        const float4 hv = *(const float4*)(&hsw[cur][12 * (tid >> 1) + 4 * (tid & 1)]);
        if (WRITE_ALL) *(float4*)(row + (size_t)(SS - 1) * HH + 4 * tid) = hv;
        else           *(float4*)(hfin + (size_t)b * HH + 4 * tid) = hv;
    }
}

// =====================================================================
__global__ __launch_bounds__(128)
void fc_k(const float* __restrict__ hlast, const float* __restrict__ fc_w,
          const float* __restrict__ fc_b, float* __restrict__ out)
{
    const int b = blockIdx.x;
    const int tid = threadIdx.x;
    __shared__ __align__(16) float h[HH];
    h[tid] = hlast[(size_t)b * HH + tid];
    __syncthreads();
    if (tid < NC) {
        float a = fc_b[tid];
        const float* wr = fc_w + tid * HH;
        #pragma unroll 4
        for (int k = 0; k < HH; ++k) a += h[k] * wr[k];
        out[(size_t)b * NC + tid] = a;
    }
}

extern "C" void kernel_launch(void* const* d_in, const int* in_sizes, int n_in,
                              void* d_out, int out_size, void* d_ws, size_t ws_size,
                              hipStream_t stream) {
    const float* x     = (const float*)d_in[0];   // (512,256,28)
    const float* w_ih0 = (const float*)d_in[1];   // (128,28)
    const float* w_hh0 = (const float*)d_in[2];   // (128,128)
    const float* b_ih0 = (const float*)d_in[3];
    const float* b_hh0 = (const float*)d_in[4];
    const float* w_ih  = (const float*)d_in[5];   // (3,128,128)
    const float* w_hh  = (const float*)d_in[6];   // (3,128,128)
    const float* b_ih  = (const float*)d_in[7];   // (3,128)
    const float* b_hh  = (const float*)d_in[8];
    const float* fc_w  = (const float*)d_in[9];   // (10,128)
    const float* fc_b  = (const float*)d_in[10];
    float* out = (float*)d_out;

    float* buf  = (float*)d_ws;                   // (B,S,H) fp32 = 64 MB
    float* hfin = buf + (size_t)BB * SS * HH;     // (B,H)

    const int PGRID = (BB * SS) / 64;             // 2048 blocks

    proj_k<28><<<PGRID, 256, 0, stream>>>(x, w_ih0, b_ih0, b_hh0, buf);
    scan_k<true><<<BB, 256, 0, stream>>>(buf, hfin, w_hh0);
    for (int l = 0; l < 3; ++l) {
        proj_k<128><<<PGRID, 256, 0, stream>>>(buf, w_ih + (size_t)l * HH * HH,
                                               b_ih + (size_t)l * HH,
                                               b_hh + (size_t)l * HH, buf);
        if (l < 2) scan_k<true ><<<BB, 256, 0, stream>>>(buf, hfin, w_hh + (size_t)l * HH * HH);
        else       scan_k<false><<<BB, 256, 0, stream>>>(buf, hfin, w_hh + (size_t)l * HH * HH);
    }
    fc_k<<<BB, 128, 0, stream>>>(hfin, fc_w, fc_b, out);
}

// Round 8
// 739.413 us; speedup vs baseline: 20.7465x; 1.0448x over previous
//
#include <hip/hip_runtime.h>

#define BB 512
#define SS 256
#define HH 128
#define NC 10

typedef float v2f __attribute__((ext_vector_type(2)));

// acc + (give from lane selected by DPP ctrl); compiles to v_mov_dpp + v_add
template<int CTRL>
__device__ __forceinline__ float dppadd(float acc, float give) {
    int t = __builtin_amdgcn_update_dpp(0, __float_as_int(give), CTRL, 0xF, 0xF, true);
    return acc + __int_as_float(t);
}

// =====================================================================
// proj_k: out[m][j] = b1[j] + b2[j] + sum_d A[m][d] * W[j][d]
// 64x128 block tile, 4x8 per thread. launch_bounds(256,1) -> budget 256.
// q-loop unroll 2 (R8: was unroll 1 anti-spill at the old 84 budget).
// =====================================================================
template<int K>
__global__ __launch_bounds__(256, 1)
void proj_k(const float* __restrict__ A, const float* __restrict__ W,
            const float* __restrict__ b1, const float* __restrict__ b2,
            float* __restrict__ out)
{
    constexpr int AS = ((K + 31) / 32) * 32 + 4;
    constexpr int KQ = K / 4;
    constexpr int KCW = (K < 32) ? K : 32;
    constexpr int WQ = KCW / 4;
    const int tid = threadIdx.x;
    const int tx = tid & 15;
    const int ty = tid >> 4;
    const size_t m0 = (size_t)blockIdx.x * 64;

    __shared__ float Arm[64 * AS];
    __shared__ float Wst[128 * 36];

    for (int idx = tid; idx < 64 * KQ; idx += 256) {
        const int row = idx / KQ, kq = idx % KQ;
        const float4 v = *(const float4*)(A + (m0 + row) * K + 4 * kq);
        *(float4*)(&Arm[row * AS + 4 * kq]) = v;
    }

    float acc[4][8];
    #pragma unroll
    for (int c = 0; c < 8; ++c) {
        const int j = tx + 16 * c;
        const float bj = b1[j] + b2[j];
        #pragma unroll
        for (int r = 0; r < 4; ++r) acc[r][c] = bj;
    }

    #pragma unroll 1
    for (int kc = 0; kc < K; kc += KCW) {
        __syncthreads();
        for (int idx = tid; idx < 128 * WQ; idx += 256) {
            const int col = idx / WQ, q = idx % WQ;
            const float4 v = *(const float4*)(W + (size_t)col * K + kc + 4 * q);
            *(float4*)(&Wst[col * 36 + 4 * q]) = v;
        }
        __syncthreads();
        #pragma unroll 2
        for (int q = 0; q < WQ; ++q) {
            float4 av[4];
            #pragma unroll
            for (int r = 0; r < 4; ++r)
                av[r] = *(const float4*)(&Arm[(ty + 16 * r) * AS + kc + 4 * q]);
            #pragma unroll
            for (int c = 0; c < 8; ++c) {
                const float4 wv = *(const float4*)(&Wst[(tx + 16 * c) * 36 + 4 * q]);
                #pragma unroll
                for (int r = 0; r < 4; ++r)
                    acc[r][c] += av[r].x * wv.x + av[r].y * wv.y
                               + av[r].z * wv.z + av[r].w * wv.w;
            }
        }
    }

    #pragma unroll
    for (int r = 0; r < 4; ++r)
        #pragma unroll
        for (int c = 0; c < 8; ++c)
            out[(m0 + ty + 16 * r) * HH + tx + 16 * c] = acc[r][c];
}

// =====================================================================
// scan_k (R8): 256 thr/row; j=tid>>4 (16 col-groups of 8), r=tid&15
// (k-chunk [8r,8r+8)). Weight-slot permutation: slot i holds column
// 8j + (i ^ (r&7)) -> reduce-scatter needs NO per-step cndmasks:
//   lvl1 xor1 (quad_perm 0xB1): v[i] += dpp(v[i^1]), keep even slots
//   lvl2 xor2 (quad_perm 0x4E): s0 += dpp(s2), s4 += dpp(s6)
//   lvl3 xor4 (row_ror 4/12 pair + 1 cndmask): s0 += sel(r&4, ror12, ror4)(s4)
//   lvl4 xor8 (row_ror:8 == xor8 in-row): s0 += dpp(s0)
// Final: lane r holds column 8j + (r&7); copies at r, r^8; writers r<8.
// No ds_swizzle -> no LDS-pipe latency in the reduce chain, no conflicts.
// h read as v2f (ds_read_b64 x4) feeding v_pk_fma_f32 directly.
// =====================================================================
template<bool WRITE_ALL>
__global__ __attribute__((amdgpu_flat_work_group_size(256, 256),
                          amdgpu_waves_per_eu(2, 2)))
void scan_k(float* __restrict__ buf, float* __restrict__ hfin,
            const float* __restrict__ w_hh)
{
    const int b   = blockIdx.x;
    const int tid = threadIdx.x;
    const int j   = tid >> 4;        // col group: cols 8j..8j+7
    const int r   = tid & 15;        // k-chunk [8r, 8r+8)
    const int g7  = r & 7;

    float* const row = buf + (size_t)b * SS * HH;

    // weights: w2[i][p] = cols pair of W[8j + (i^g7)][8r + 2p..]
    v2f w2[8][4];
    #pragma unroll
    for (int i = 0; i < 8; ++i) {
        const v2f* wr = (const v2f*)(w_hh + (size_t)(8 * j + (i ^ g7)) * HH + 8 * r);
        w2[i][0] = wr[0]; w2[i][1] = wr[1]; w2[i][2] = wr[2]; w2[i][3] = wr[3];
    }

    __shared__ float hsw[2][192];        // h[k] at word 12*(k>>3)+(k&7)
    __shared__ float xwl[2][8][HH];      // 8-step xw double buffer

    if (tid < 192) hsw[0][tid] = 0.f;
    const int t   = tid >> 5;            // staging: step-in-chunk
    const int pos = (tid & 31) * 4;      // staging: column (float4)
    {   // stage xw for steps 0..7
        const float4 v = *(const float4*)(row + (size_t)t * HH + pos);
        *(float4*)(&xwl[0][t][pos]) = v;
    }
    __syncthreads();

    const int cc  = 8 * j + g7;          // column this lane finalizes
    const int wsw = 12 * j + g7;         // its swizzled LDS word

    int cur = 0;
    for (int s = 0; s < SS; ++s) {
        const int ph = s & 7, cb = (s >> 3) & 1;
        const bool do_stage = (ph == 0) && (s + 8 < SS);
        float4 stg;
        if (do_stage)
            stg = *(const float4*)(row + (size_t)(s + 8 + t) * HH + pos);
        if (WRITE_ALL && s > 0 && tid < 32) {   // store h_{s-1}
            const float4 hv = *(const float4*)(&hsw[cur][12 * (tid >> 1) + 4 * (tid & 1)]);
            *(float4*)(row + (size_t)(s - 1) * HH + 4 * tid) = hv;
        }
        const float myxw = xwl[cb][ph][cc];     // independent: issue early

        // MAC: 8 permuted cols x 8 k (4 packed pairs each)
        const v2f* hb = (const v2f*)&hsw[cur][12 * r];
        const v2f hp0 = hb[0], hp1 = hb[1], hp2 = hb[2], hp3 = hb[3];
        float v[8];
        #pragma unroll
        for (int i = 0; i < 8; ++i) {
            v2f a = hp0 * w2[i][0];
            a += hp1 * w2[i][1];
            a += hp2 * w2[i][2];
            a += hp3 * w2[i][3];
            v[i] = a.x + a.y;
        }

        // aligned reduce-scatter (no cndmasks)
        float s0 = dppadd<0xB1>(v[0], v[1]);    // xor1
        float s2 = dppadd<0xB1>(v[2], v[3]);
        float s4 = dppadd<0xB1>(v[4], v[5]);
        float s6 = dppadd<0xB1>(v[6], v[7]);
        s0 = dppadd<0x4E>(s0, s2);              // xor2
        s4 = dppadd<0x4E>(s4, s6);
        {   // xor4 via row_ror 4 / 12
            int t1 = __builtin_amdgcn_update_dpp(0, __float_as_int(s4), 0x124, 0xF, 0xF, true);
            int t2 = __builtin_amdgcn_update_dpp(0, __float_as_int(s4), 0x12C, 0xF, 0xF, true);
            s0 += __int_as_float((r & 4) ? t2 : t1);
        }
        s0 = dppadd<0x128>(s0, s0);             // xor8 (row_ror:8)

        const float z = s0 + myxw;
        const float e = __expf(2.f * z);
        const float hnew = 1.f - 2.f * __builtin_amdgcn_rcpf(1.f + e);  // tanh(z)

        if (r < 8) hsw[cur ^ 1][wsw] = hnew;
        if (do_stage) *(float4*)(&xwl[cb ^ 1][t][pos]) = stg;
        __syncthreads();
        cur ^= 1;
    }

    if (tid < 32) {   // final h (step SS-1) lives in hsw[cur]
        const float4 hv = *(const float4*)(&hsw[cur][12 * (tid >> 1) + 4 * (tid & 1)]);
        if (WRITE_ALL) *(float4*)(row + (size_t)(SS - 1) * HH + 4 * tid) = hv;
        else           *(float4*)(hfin + (size_t)b * HH + 4 * tid) = hv;
    }
}

// =====================================================================
__global__ __launch_bounds__(128)
void fc_k(const float* __restrict__ hlast, const float* __restrict__ fc_w,
          const float* __restrict__ fc_b, float* __restrict__ out)
{
    const int b = blockIdx.x;
    const int tid = threadIdx.x;
    __shared__ __align__(16) float h[HH];
    h[tid] = hlast[(size_t)b * HH + tid];
    __syncthreads();
    if (tid < NC) {
        float a = fc_b[tid];
        const float* wr = fc_w + tid * HH;
        #pragma unroll 4
        for (int k = 0; k < HH; ++k) a += h[k] * wr[k];
        out[(size_t)b * NC + tid] = a;
    }
}

extern "C" void kernel_launch(void* const* d_in, const int* in_sizes, int n_in,
                              void* d_out, int out_size, void* d_ws, size_t ws_size,
                              hipStream_t stream) {
    const float* x     = (const float*)d_in[0];   // (512,256,28)
    const float* w_ih0 = (const float*)d_in[1];   // (128,28)
    const float* w_hh0 = (const float*)d_in[2];   // (128,128)
    const float* b_ih0 = (const float*)d_in[3];
    const float* b_hh0 = (const float*)d_in[4];
    const float* w_ih  = (const float*)d_in[5];   // (3,128,128)
    const float* w_hh  = (const float*)d_in[6];   // (3,128,128)
    const float* b_ih  = (const float*)d_in[7];   // (3,128)
    const float* b_hh  = (const float*)d_in[8];
    const float* fc_w  = (const float*)d_in[9];   // (10,128)
    const float* fc_b  = (const float*)d_in[10];
    float* out = (float*)d_out;

    float* buf  = (float*)d_ws;                   // (B,S,H) fp32 = 64 MB
    float* hfin = buf + (size_t)BB * SS * HH;     // (B,H)

    const int PGRID = (BB * SS) / 64;             // 2048 blocks

    proj_k<28><<<PGRID, 256, 0, stream>>>(x, w_ih0, b_ih0, b_hh0, buf);
    scan_k<true><<<BB, 256, 0, stream>>>(buf, hfin, w_hh0);
    for (int l = 0; l < 3; ++l) {
        proj_k<128><<<PGRID, 256, 0, stream>>>(buf, w_ih + (size_t)l * HH * HH,
                                               b_ih + (size_t)l * HH,
                                               b_hh + (size_t)l * HH, buf);
        if (l < 2) scan_k<true ><<<BB, 256, 0, stream>>>(buf, hfin, w_hh + (size_t)l * HH * HH);
        else       scan_k<false><<<BB, 256, 0, stream>>>(buf, hfin, w_hh + (size_t)l * HH * HH);
    }
    fc_k<<<BB, 128, 0, stream>>>(hfin, fc_w, fc_b, out);
}

// Round 9
// 719.682 us; speedup vs baseline: 21.3153x; 1.0274x over previous
//
#include <hip/hip_runtime.h>

#define BB 512
#define SS 256
#define HH 128
#define NC 10

typedef float v2f __attribute__((ext_vector_type(2)));

// acc + (give from lane selected by DPP ctrl)
template<int CTRL>
__device__ __forceinline__ float dppadd(float acc, float give) {
    int t = __builtin_amdgcn_update_dpp(0, __float_as_int(give), CTRL, 0xF, 0xF, true);
    return acc + __int_as_float(t);
}

// cndmask-free reduce-scatter over the 16-lane group (R8-verified).
// Input v[8] in permuted slot order (slot i = column 8j + (i^(r&7))).
// Returns full sum for column 8j + (r&7); copies at lanes r and r^8.
__device__ __forceinline__ float red_scatter(const float v[8], int r) {
    float s0 = dppadd<0xB1>(v[0], v[1]);    // xor1
    float s2 = dppadd<0xB1>(v[2], v[3]);
    float s4 = dppadd<0xB1>(v[4], v[5]);
    float s6 = dppadd<0xB1>(v[6], v[7]);
    s0 = dppadd<0x4E>(s0, s2);              // xor2
    s4 = dppadd<0x4E>(s4, s6);
    {   // xor4 via row_ror 4 / 12
        int t1 = __builtin_amdgcn_update_dpp(0, __float_as_int(s4), 0x124, 0xF, 0xF, true);
        int t2 = __builtin_amdgcn_update_dpp(0, __float_as_int(s4), 0x12C, 0xF, 0xF, true);
        s0 += __int_as_float((r & 4) ? t2 : t1);
    }
    s0 = dppadd<0x128>(s0, s0);             // xor8 (row_ror:8)
    return s0;
}

// =====================================================================
// proj_k: out[m][j] = sum_d A[m][d] * W[j][d]   (NO bias — scans add it)
// Only used for layer 0 (K=28) now.
// =====================================================================
template<int K>
__global__ __launch_bounds__(256, 1)
void proj_k(const float* __restrict__ A, const float* __restrict__ W,
            float* __restrict__ out)
{
    constexpr int AS = ((K + 31) / 32) * 32 + 4;
    constexpr int KQ = K / 4;
    constexpr int KCW = (K < 32) ? K : 32;
    constexpr int WQ = KCW / 4;
    const int tid = threadIdx.x;
    const int tx = tid & 15;
    const int ty = tid >> 4;
    const size_t m0 = (size_t)blockIdx.x * 64;

    __shared__ float Arm[64 * AS];
    __shared__ float Wst[128 * 36];

    for (int idx = tid; idx < 64 * KQ; idx += 256) {
        const int row = idx / KQ, kq = idx % KQ;
        const float4 v = *(const float4*)(A + (m0 + row) * K + 4 * kq);
        *(float4*)(&Arm[row * AS + 4 * kq]) = v;
    }

    float acc[4][8];
    #pragma unroll
    for (int c = 0; c < 8; ++c)
        #pragma unroll
        for (int r = 0; r < 4; ++r) acc[r][c] = 0.f;

    #pragma unroll 1
    for (int kc = 0; kc < K; kc += KCW) {
        __syncthreads();
        for (int idx = tid; idx < 128 * WQ; idx += 256) {
            const int col = idx / WQ, q = idx % WQ;
            const float4 v = *(const float4*)(W + (size_t)col * K + kc + 4 * q);
            *(float4*)(&Wst[col * 36 + 4 * q]) = v;
        }
        __syncthreads();
        #pragma unroll 2
        for (int q = 0; q < WQ; ++q) {
            float4 av[4];
            #pragma unroll
            for (int r = 0; r < 4; ++r)
                av[r] = *(const float4*)(&Arm[(ty + 16 * r) * AS + kc + 4 * q]);
            #pragma unroll
            for (int c = 0; c < 8; ++c) {
                const float4 wv = *(const float4*)(&Wst[(tx + 16 * c) * 36 + 4 * q]);
                #pragma unroll
                for (int r = 0; r < 4; ++r)
                    acc[r][c] += av[r].x * wv.x + av[r].y * wv.y
                               + av[r].z * wv.z + av[r].w * wv.w;
            }
        }
    }

    #pragma unroll
    for (int r = 0; r < 4; ++r)
        #pragma unroll
        for (int c = 0; c < 8; ++c)
            out[(m0 + ty + 16 * r) * HH + tx + 16 * c] = acc[r][c];
}

// =====================================================================
// scan_k (R9, fused): per step s computes
//   h_s = tanh(bias + xw_l[s] + h_{s-1} @ W_hh^T)
// and, for !LAST, also the NEXT layer's projection from the same
// register-resident h fragments (off the critical path):
//   buf[s-1] = h_{s-1} @ W_ih_next^T        (bias-free; next scan adds it)
// This removes the standalone proj_k for layers 1..3 and the h
// writeback. Both W_hh and W_ih_next live in VGPRs (64+64 floats) in
// the permuted-slot layout feeding the cndmask-free reduce-scatter.
// In-place: slice X read (staged) at step X-8, written at step X+1.
// =====================================================================
template<bool LAST>
__global__ __attribute__((amdgpu_flat_work_group_size(256, 256),
                          amdgpu_waves_per_eu(2, 2)))
void scan_k(float* __restrict__ buf, float* __restrict__ hfin,
            const float* __restrict__ w_hh, const float* __restrict__ w_ih_next,
            const float* __restrict__ b_ih_l, const float* __restrict__ b_hh_l)
{
    const int b   = blockIdx.x;
    const int tid = threadIdx.x;
    const int j   = tid >> 4;        // col group: cols 8j..8j+7
    const int r   = tid & 15;        // k-chunk [8r, 8r+8)
    const int g7  = r & 7;

    float* const row = buf + (size_t)b * SS * HH;
    const int cc  = 8 * j + g7;      // column this lane finalizes
    const int wsw = 12 * j + g7;     // its swizzled LDS word
    const float bias = b_ih_l[cc] + b_hh_l[cc];

    // permuted weights: slot i = column 8j + (i^g7), k-pair p
    v2f wh[8][4], wi[8][4];
    #pragma unroll
    for (int i = 0; i < 8; ++i) {
        const v2f* p = (const v2f*)(w_hh + (size_t)(8 * j + (i ^ g7)) * HH + 8 * r);
        wh[i][0] = p[0]; wh[i][1] = p[1]; wh[i][2] = p[2]; wh[i][3] = p[3];
    }
    if (!LAST) {
        #pragma unroll
        for (int i = 0; i < 8; ++i) {
            const v2f* p = (const v2f*)(w_ih_next + (size_t)(8 * j + (i ^ g7)) * HH + 8 * r);
            wi[i][0] = p[0]; wi[i][1] = p[1]; wi[i][2] = p[2]; wi[i][3] = p[3];
        }
    }

    __shared__ float hsw[2][192];        // h[k] at word 12*(k>>3)+(k&7)
    __shared__ float xwl[2][8][HH];      // 8-step xw double buffer

    if (tid < 192) hsw[0][tid] = 0.f;
    const int t   = tid >> 5;            // staging: step-in-chunk
    const int pos = (tid & 31) * 4;      // staging: column (float4)
    {   // stage xw for steps 0..7
        const float4 v = *(const float4*)(row + (size_t)t * HH + pos);
        *(float4*)(&xwl[0][t][pos]) = v;
    }
    __syncthreads();

    int cur = 0;
    for (int s = 0; s < SS; ++s) {
        const int ph = s & 7, cb = (s >> 3) & 1;
        const bool do_stage = (ph == 0) && (s + 8 < SS);
        float4 stg;
        if (do_stage)
            stg = *(const float4*)(row + (size_t)(s + 8 + t) * HH + pos);
        const float myxw = xwl[cb][ph][cc] + bias;

        // h_{s-1} fragments (shared by both MACs)
        const v2f* hb = (const v2f*)&hsw[cur][12 * r];
        const v2f hp0 = hb[0], hp1 = hb[1], hp2 = hb[2], hp3 = hb[3];

        // recurrence MAC (critical path)
        float v[8];
        #pragma unroll
        for (int i = 0; i < 8; ++i) {
            v2f a = hp0 * wh[i][0];
            a += hp1 * wh[i][1];
            a += hp2 * wh[i][2];
            a += hp3 * wh[i][3];
            v[i] = a.x + a.y;
        }
        const float z = red_scatter(v, r) + myxw;
        const float e = __expf(2.f * z);
        const float hnew = 1.f - 2.f * __builtin_amdgcn_rcpf(1.f + e);  // tanh(z)
        if (r < 8) hsw[cur ^ 1][wsw] = hnew;

        // fused next-layer projection of h_{s-1} (latency-tolerant)
        if (!LAST && s > 0) {
            float u[8];
            #pragma unroll
            for (int i = 0; i < 8; ++i) {
                v2f a = hp0 * wi[i][0];
                a += hp1 * wi[i][1];
                a += hp2 * wi[i][2];
                a += hp3 * wi[i][3];
                u[i] = a.x + a.y;
            }
            const float xwn = red_scatter(u, r);
            if (r < 8) row[(size_t)(s - 1) * HH + cc] = xwn;
        }

        if (do_stage) *(float4*)(&xwl[cb ^ 1][t][pos]) = stg;
        __syncthreads();
        cur ^= 1;
    }

    // epilogue: h_{SS-1} lives in hsw[cur]
    if (!LAST) {
        const v2f* hb = (const v2f*)&hsw[cur][12 * r];
        const v2f hp0 = hb[0], hp1 = hb[1], hp2 = hb[2], hp3 = hb[3];
        float u[8];
        #pragma unroll
        for (int i = 0; i < 8; ++i) {
            v2f a = hp0 * wi[i][0];
            a += hp1 * wi[i][1];
            a += hp2 * wi[i][2];
            a += hp3 * wi[i][3];
            u[i] = a.x + a.y;
        }
        const float xwn = red_scatter(u, r);
        if (r < 8) row[(size_t)(SS - 1) * HH + cc] = xwn;
    } else if (tid < 32) {
        const float4 hv = *(const float4*)(&hsw[cur][12 * (tid >> 1) + 4 * (tid & 1)]);
        *(float4*)(hfin + (size_t)b * HH + 4 * tid) = hv;
    }
}

// =====================================================================
__global__ __launch_bounds__(128)
void fc_k(const float* __restrict__ hlast, const float* __restrict__ fc_w,
          const float* __restrict__ fc_b, float* __restrict__ out)
{
    const int b = blockIdx.x;
    const int tid = threadIdx.x;
    __shared__ __align__(16) float h[HH];
    h[tid] = hlast[(size_t)b * HH + tid];
    __syncthreads();
    if (tid < NC) {
        float a = fc_b[tid];
        const float* wr = fc_w + tid * HH;
        #pragma unroll 4
        for (int k = 0; k < HH; ++k) a += h[k] * wr[k];
        out[(size_t)b * NC + tid] = a;
    }
}

extern "C" void kernel_launch(void* const* d_in, const int* in_sizes, int n_in,
                              void* d_out, int out_size, void* d_ws, size_t ws_size,
                              hipStream_t stream) {
    const float* x     = (const float*)d_in[0];   // (512,256,28)
    const float* w_ih0 = (const float*)d_in[1];   // (128,28)
    const float* w_hh0 = (const float*)d_in[2];   // (128,128)
    const float* b_ih0 = (const float*)d_in[3];
    const float* b_hh0 = (const float*)d_in[4];
    const float* w_ih  = (const float*)d_in[5];   // (3,128,128)
    const float* w_hh  = (const float*)d_in[6];   // (3,128,128)
    const float* b_ih  = (const float*)d_in[7];   // (3,128)
    const float* b_hh  = (const float*)d_in[8];
    const float* fc_w  = (const float*)d_in[9];   // (10,128)
    const float* fc_b  = (const float*)d_in[10];
    float* out = (float*)d_out;

    float* buf  = (float*)d_ws;                   // (B,S,H) fp32 = 64 MB
    float* hfin = buf + (size_t)BB * SS * HH;     // (B,H)

    // layer 0 input projection (bias-free; scan adds bias)
    proj_k<28><<<(BB * SS) / 64, 256, 0, stream>>>(x, w_ih0, buf);
    // layer 0 scan, fused with layer-1 projection
    scan_k<false><<<BB, 256, 0, stream>>>(buf, hfin, w_hh0, w_ih,
                                          b_ih0, b_hh0);
    // layer 1 scan (+proj of layer 2), layer 2 scan (+proj of layer 3)
    scan_k<false><<<BB, 256, 0, stream>>>(buf, hfin, w_hh,
                                          w_ih + (size_t)1 * HH * HH,
                                          b_ih, b_hh);
    scan_k<false><<<BB, 256, 0, stream>>>(buf, hfin, w_hh + (size_t)1 * HH * HH,
                                          w_ih + (size_t)2 * HH * HH,
                                          b_ih + HH, b_hh + HH);
    // layer 3 scan (LAST: only final h)
    scan_k<true><<<BB, 256, 0, stream>>>(buf, hfin, w_hh + (size_t)2 * HH * HH,
                                         nullptr, b_ih + 2 * HH, b_hh + 2 * HH);
    fc_k<<<BB, 128, 0, stream>>>(hfin, fc_w, fc_b, out);
}